// Round 10
// baseline (321.347 us; speedup 1.0000x reference)
//
#include <hip/hip_runtime.h>

// LightGCN propagation, CSR-gather, bf16 intermediates, unified row space.
// R10: 16B/lane gathers (8 lanes/row, uint4) in all agg kernels — halves
// VMEM instruction count vs R9's 8B/lane. Flag/compact restructured:
//   A: partition hist + f32->bf16 convert + out_h0 + bucket bitmap/flags.
//   S: 1-block scan of partition totals.
//   B: partition scatter (LDS hist + 1 returning atomic per block-partition)
//      + fused edge-sweep flagging (bitmap test, plain stores).
//   C: per-partition CSR build (rp+entries) + fused flag compaction.
//   agg1 (all rows) ; agg2 (listed rows) + out+=0.25*H1 ; aggout (+H2 add
//   in-thread, single RMW on out).

#define N_USERS 200000
#define N_ITEMS 100000
#define N_EDGES 1000000
#define DIM 64
#define BATCH 8192
#define NTOT (N_USERS + N_ITEMS)          // 300000 rows
#define NOUT (3 * BATCH)                  // 24576 output rows
#define NPART 293                         // ceil(NTOT / 1024)
#define PLOCAL 1024

#define HA 489                            // 8 edges/thread blocks
#define CB (NTOT * DIM / 8 / 256)         // 9375 convert blocks
#define OB (NOUT * 16 / 256)              // 1536 out_h0 / out_add blocks
#define BB ((NOUT + 255) / 256)           // 96 bitmap blocks
#define AB8 (NTOT / 32)                   // 9375 agg blocks (8 rows/wave)
#define CPB ((NTOT / 4 + 255) / 256)      // 293 compact blocks

// ---------- bf16 helpers ----------
__device__ __forceinline__ unsigned f2bf(float f) {   // round-to-nearest-even
    unsigned u = __float_as_uint(f);
    return (u + 0x7fffu + ((u >> 16) & 1u)) >> 16;
}
__device__ __forceinline__ uint2 pack4(float4 v) {
    uint2 o;
    o.x = f2bf(v.x) | (f2bf(v.y) << 16);
    o.y = f2bf(v.z) | (f2bf(v.w) << 16);
    return o;
}
__device__ __forceinline__ void fma8(float4& a, float4& b, uint4 v, float w) {
    a.x += __uint_as_float(v.x << 16) * w;
    a.y += __uint_as_float(v.x & 0xffff0000u) * w;
    a.z += __uint_as_float(v.y << 16) * w;
    a.w += __uint_as_float(v.y & 0xffff0000u) * w;
    b.x += __uint_as_float(v.z << 16) * w;
    b.y += __uint_as_float(v.z & 0xffff0000u) * w;
    b.z += __uint_as_float(v.w << 16) * w;
    b.w += __uint_as_float(v.w & 0xffff0000u) * w;
}
__device__ __forceinline__ int out_bucket(int orow, const int* users,
                                          const int* pos, const int* neg) {
    int seg = orow >> 13;
    int b = orow & (BATCH - 1);
    if (seg == 0) return users[b];
    if (seg == 1) return N_USERS + pos[b];
    return N_USERS + neg[b];
}

// ---------------- A: partition hist + convert + out_h0 + bitmap ----------------
__global__ void fused_pre_kernel(const int* __restrict__ eu,
                                 const int* __restrict__ ei,
                                 int* __restrict__ partTotals,
                                 const float4* __restrict__ uf4,
                                 const float4* __restrict__ if4,
                                 unsigned short* __restrict__ F0,
                                 const float* __restrict__ u_feat,
                                 const float* __restrict__ i_feat,
                                 const int* __restrict__ users,
                                 const int* __restrict__ pos,
                                 const int* __restrict__ neg,
                                 float* __restrict__ out,
                                 int* __restrict__ bitmap,
                                 int* __restrict__ flags)
{
    __shared__ int lh[NPART];
    int bid = blockIdx.x;
    if (bid < HA) {
        for (int k = threadIdx.x; k < NPART; k += 256) lh[k] = 0;
        __syncthreads();
        int e0 = (bid * 256 + threadIdx.x) * 8;
        if (e0 < N_EDGES) {
            int4 u0 = *reinterpret_cast<const int4*>(eu + e0);
            int4 u1 = *reinterpret_cast<const int4*>(eu + e0 + 4);
            int4 i0 = *reinterpret_cast<const int4*>(ei + e0);
            int4 i1 = *reinterpret_cast<const int4*>(ei + e0 + 4);
            atomicAdd(&lh[u0.x >> 10], 1);
            atomicAdd(&lh[u0.y >> 10], 1);
            atomicAdd(&lh[u0.z >> 10], 1);
            atomicAdd(&lh[u0.w >> 10], 1);
            atomicAdd(&lh[u1.x >> 10], 1);
            atomicAdd(&lh[u1.y >> 10], 1);
            atomicAdd(&lh[u1.z >> 10], 1);
            atomicAdd(&lh[u1.w >> 10], 1);
            atomicAdd(&lh[(N_USERS + i0.x) >> 10], 1);
            atomicAdd(&lh[(N_USERS + i0.y) >> 10], 1);
            atomicAdd(&lh[(N_USERS + i0.z) >> 10], 1);
            atomicAdd(&lh[(N_USERS + i0.w) >> 10], 1);
            atomicAdd(&lh[(N_USERS + i1.x) >> 10], 1);
            atomicAdd(&lh[(N_USERS + i1.y) >> 10], 1);
            atomicAdd(&lh[(N_USERS + i1.z) >> 10], 1);
            atomicAdd(&lh[(N_USERS + i1.w) >> 10], 1);
        }
        __syncthreads();
        for (int k = threadIdx.x; k < NPART; k += 256) {
            int v = lh[k];
            if (v) atomicAdd(&partTotals[k], v);   // fire-and-forget
        }
    } else if (bid < HA + CB) {
        int j = (bid - HA) * 256 + threadIdx.x;      // [0, 2.4M)
        int f4 = j * 2;
        const int NU4 = N_USERS * DIM / 4;           // 3.2M
        float4 a, b;
        if (f4 < NU4) { a = uf4[f4]; b = uf4[f4 + 1]; }
        else          { a = if4[f4 - NU4]; b = if4[f4 - NU4 + 1]; }
        uint2 pa = pack4(a), pb = pack4(b);
        *reinterpret_cast<uint4*>(F0 + (size_t)j * 8) =
            make_uint4(pa.x, pa.y, pb.x, pb.y);
    } else if (bid < HA + CB + OB) {
        int idx = (bid - HA - CB) * 256 + threadIdx.x;
        int row = idx >> 4;
        if (row >= NOUT) return;
        int d4 = (idx & 15) << 2;
        int seg = row >> 13;
        int b = row & (BATCH - 1);
        const float* src;
        if (seg == 0)      src = u_feat + (size_t)users[b] * DIM;
        else if (seg == 1) src = i_feat + (size_t)pos[b]   * DIM;
        else               src = i_feat + (size_t)neg[b]   * DIM;
        float4 v = *reinterpret_cast<const float4*>(src + d4);
        v.x *= 0.25f; v.y *= 0.25f; v.z *= 0.25f; v.w *= 0.25f;
        *reinterpret_cast<float4*>(out + (size_t)row * DIM + d4) = v;
    } else {
        // bucket bitmap + self-flags (plain stores, benign races)
        int t = (bid - HA - CB - OB) * 256 + threadIdx.x;
        if (t >= NOUT) return;
        int bucket = out_bucket(t, users, pos, neg);
        bitmap[bucket] = 1;
        flags[bucket] = 1;
    }
}

// ---------------- S: scan partition totals ----------------
__global__ void part_scan_kernel(const int* __restrict__ partTotals,
                                 int* __restrict__ partStart,
                                 int* __restrict__ gcur)
{
    __shared__ int s[512];
    int t = threadIdx.x;
    s[t] = (t < NPART) ? partTotals[t] : 0;
    __syncthreads();
    for (int off = 1; off < 512; off <<= 1) {
        int x = (t >= off) ? s[t - off] : 0;
        __syncthreads();
        s[t] += x;
        __syncthreads();
    }
    if (t < NPART) {
        int st = (t == 0) ? 0 : s[t - 1];
        partStart[t] = st;
        gcur[t] = st;
    }
    if (t == NPART) partStart[NPART] = s[NPART - 1];   // == 2*N_EDGES
}

// ---------------- B: partition scatter + edge-sweep flagging ----------------
__global__ void partition_kernel(const int* __restrict__ eu,
                                 const int* __restrict__ ei,
                                 const float* __restrict__ w,
                                 int* __restrict__ gcur,
                                 uint2* __restrict__ partBuf,
                                 const int* __restrict__ bitmap,
                                 int* __restrict__ flags)
{
    __shared__ int lh[NPART];
    __shared__ int lcur[NPART];
    int bid = blockIdx.x, t = threadIdx.x;
    if (bid < HA) {
        for (int k = t; k < NPART; k += 256) lh[k] = 0;
        __syncthreads();
        int e0 = (bid * 256 + t) * 8;
        bool act = e0 < N_EDGES;
        int4 u0, u1, i0, i1;
        if (act) {
            u0 = *reinterpret_cast<const int4*>(eu + e0);
            u1 = *reinterpret_cast<const int4*>(eu + e0 + 4);
            i0 = *reinterpret_cast<const int4*>(ei + e0);
            i1 = *reinterpret_cast<const int4*>(ei + e0 + 4);
            atomicAdd(&lh[u0.x >> 10], 1);
            atomicAdd(&lh[u0.y >> 10], 1);
            atomicAdd(&lh[u0.z >> 10], 1);
            atomicAdd(&lh[u0.w >> 10], 1);
            atomicAdd(&lh[u1.x >> 10], 1);
            atomicAdd(&lh[u1.y >> 10], 1);
            atomicAdd(&lh[u1.z >> 10], 1);
            atomicAdd(&lh[u1.w >> 10], 1);
            atomicAdd(&lh[(N_USERS + i0.x) >> 10], 1);
            atomicAdd(&lh[(N_USERS + i0.y) >> 10], 1);
            atomicAdd(&lh[(N_USERS + i0.z) >> 10], 1);
            atomicAdd(&lh[(N_USERS + i0.w) >> 10], 1);
            atomicAdd(&lh[(N_USERS + i1.x) >> 10], 1);
            atomicAdd(&lh[(N_USERS + i1.y) >> 10], 1);
            atomicAdd(&lh[(N_USERS + i1.z) >> 10], 1);
            atomicAdd(&lh[(N_USERS + i1.w) >> 10], 1);
        }
        __syncthreads();
        for (int k = t; k < NPART; k += 256) {
            int v = lh[k];
            lcur[k] = v ? atomicAdd(&gcur[k], v) : 0;
        }
        __syncthreads();
        if (act) {
            float4 wa = *reinterpret_cast<const float4*>(w + e0);
            float4 wb = *reinterpret_cast<const float4*>(w + e0 + 4);
            int us[8] = {u0.x, u0.y, u0.z, u0.w, u1.x, u1.y, u1.z, u1.w};
            int is[8] = {i0.x, i0.y, i0.z, i0.w, i1.x, i1.y, i1.z, i1.w};
            float ws[8] = {wa.x, wa.y, wa.z, wa.w, wb.x, wb.y, wb.z, wb.w};
            #pragma unroll
            for (int j = 0; j < 8; ++j) {
                int bu = us[j];
                int bi = N_USERS + is[j];
                unsigned wbits = __float_as_uint(ws[j]);
                int su = atomicAdd(&lcur[bu >> 10], 1);    // LDS
                partBuf[su] = make_uint2((unsigned)(bu & 1023) | ((unsigned)bi << 10), wbits);
                int si = atomicAdd(&lcur[bi >> 10], 1);    // LDS
                partBuf[si] = make_uint2((unsigned)(bi & 1023) | ((unsigned)bu << 10), wbits);
            }
        }
    } else {
        // edge-sweep flagging: neighbors of bucket rows
        int e0 = ((bid - HA) * 256 + t) * 8;
        if (e0 >= N_EDGES) return;
        int4 u0 = *reinterpret_cast<const int4*>(eu + e0);
        int4 u1 = *reinterpret_cast<const int4*>(eu + e0 + 4);
        int4 i0 = *reinterpret_cast<const int4*>(ei + e0);
        int4 i1 = *reinterpret_cast<const int4*>(ei + e0 + 4);
        int us[8] = {u0.x, u0.y, u0.z, u0.w, u1.x, u1.y, u1.z, u1.w};
        int is[8] = {i0.x, i0.y, i0.z, i0.w, i1.x, i1.y, i1.z, i1.w};
        #pragma unroll
        for (int j = 0; j < 8; ++j) {
            if (bitmap[us[j]]) flags[N_USERS + is[j]] = 1;
            if (bitmap[N_USERS + is[j]]) flags[us[j]] = 1;
        }
    }
}

// ---------------- C: per-partition CSR build + flag compaction ----------------
__global__ void build_csr_kernel(const int* __restrict__ partStart,
                                 const uint2* __restrict__ partBuf,
                                 int* __restrict__ rp,
                                 int2* __restrict__ entries,
                                 const int* __restrict__ flags,
                                 int* __restrict__ list,
                                 int* __restrict__ count)
{
    __shared__ int h[PLOCAL];
    __shared__ int cur[PLOCAL];
    __shared__ int s[256];
    int t = threadIdx.x;
    if (blockIdx.x < NPART) {
        int p = blockIdx.x;
        int base = partStart[p], end = partStart[p + 1];
        h[t * 4 + 0] = 0; h[t * 4 + 1] = 0; h[t * 4 + 2] = 0; h[t * 4 + 3] = 0;
        __syncthreads();
        for (int r = base + t; r < end; r += 256)
            atomicAdd(&h[partBuf[r].x & 1023], 1);
        __syncthreads();
        int h0 = h[t * 4], h1 = h[t * 4 + 1], h2 = h[t * 4 + 2], h3 = h[t * 4 + 3];
        s[t] = h0 + h1 + h2 + h3;
        __syncthreads();
        for (int off = 1; off < 256; off <<= 1) {
            int x = (t >= off) ? s[t - off] : 0;
            __syncthreads();
            s[t] += x;
            __syncthreads();
        }
        int b0 = base + ((t == 0) ? 0 : s[t - 1]);
        cur[t * 4 + 0] = b0;
        cur[t * 4 + 1] = b0 + h0;
        cur[t * 4 + 2] = b0 + h0 + h1;
        cur[t * 4 + 3] = b0 + h0 + h1 + h2;
        int gb = p * PLOCAL + t * 4;
        #pragma unroll
        for (int k = 0; k < 4; ++k)
            if (gb + k <= NTOT) rp[gb + k] = cur[t * 4 + k];
        __syncthreads();
        for (int r = base + t; r < end; r += 256) {
            uint2 rec = partBuf[r];
            int b = rec.x & 1023;
            int col = rec.x >> 10;
            int slot = atomicAdd(&cur[b], 1);              // LDS
            entries[slot] = make_int2(col, (int)rec.y);
        }
    } else {
        // compaction of flags -> row list
        int idx = ((blockIdx.x - NPART) * 256 + t) * 4;
        if (idx >= NTOT) return;
        int4 f = *reinterpret_cast<const int4*>(flags + idx);
        int loc[4]; int k = 0;
        if (f.x) loc[k++] = idx;
        if (f.y) loc[k++] = idx + 1;
        if (f.z) loc[k++] = idx + 2;
        if (f.w) loc[k++] = idx + 3;
        if (k) {
            int base = atomicAdd(count, k);
            for (int m = 0; m < k; ++m) list[base + m] = loc[m];
        }
    }
}

// ---------------- agg core: 8 rows/wave, 16B/lane gathers ----------------
#define GATH8(idx, A, B)                                                      \
    {                                                                         \
        int c = __shfl(e.x, qb + (idx));                                      \
        float ww = __int_as_float(__shfl(e.y, qb + (idx)));                   \
        uint4 v = *reinterpret_cast<const uint4*>(                            \
            src + (size_t)c * DIM + l8 * 8);                                  \
        fma8(A, B, v, ww);                                                    \
    }

__device__ __forceinline__ void agg_row8(int row, int l8, int g8,
                                         const int* __restrict__ rp,
                                         const int2* __restrict__ entries,
                                         const unsigned short* __restrict__ src,
                                         float4& sa, float4& sb)
{
    int beg = rp[row];
    int end = rp[row + 1];
    int cnt = end - beg;
    int qb = g8 << 3;
    float4 a0 = {0,0,0,0}, a1 = {0,0,0,0}, a2 = {0,0,0,0}, a3 = {0,0,0,0};
    float4 b0 = {0,0,0,0}, b1 = {0,0,0,0}, b2 = {0,0,0,0}, b3 = {0,0,0,0};
    for (int base = 0; base < cnt; base += 8) {
        int rem = min(8, cnt - base);
        int2 e = make_int2(0, 0);
        if (l8 < rem) e = entries[beg + base + l8];
        int j = 0;
        for (; j + 7 < rem; j += 8) {
            GATH8(j + 0, a0, b0) GATH8(j + 1, a1, b1)
            GATH8(j + 2, a2, b2) GATH8(j + 3, a3, b3)
            GATH8(j + 4, a0, b0) GATH8(j + 5, a1, b1)
            GATH8(j + 6, a2, b2) GATH8(j + 7, a3, b3)
        }
        if (j + 3 < rem) {
            GATH8(j + 0, a0, b0) GATH8(j + 1, a1, b1)
            GATH8(j + 2, a2, b2) GATH8(j + 3, a3, b3)
            j += 4;
        }
        if (j + 1 < rem) {
            GATH8(j + 0, a0, b0) GATH8(j + 1, a1, b1)
            j += 2;
        }
        if (j < rem) GATH8(j, a2, b2)
    }
    sa.x = (a0.x + a1.x) + (a2.x + a3.x);
    sa.y = (a0.y + a1.y) + (a2.y + a3.y);
    sa.z = (a0.z + a1.z) + (a2.z + a3.z);
    sa.w = (a0.w + a1.w) + (a2.w + a3.w);
    sb.x = (b0.x + b1.x) + (b2.x + b3.x);
    sb.y = (b0.y + b1.y) + (b2.y + b3.y);
    sb.z = (b0.z + b1.z) + (b2.z + b3.z);
    sb.w = (b0.w + b1.w) + (b2.w + b3.w);
}

// ---------------- layer 1 (all rows) ----------------
__global__ void agg1_kernel(const int* __restrict__ rp,
                            const int2* __restrict__ entries,
                            const unsigned short* __restrict__ F0,
                            unsigned short* __restrict__ H1)
{
    int gid = blockIdx.x * 256 + threadIdx.x;
    int lane = gid & 63;
    int g8 = lane >> 3;
    int l8 = lane & 7;
    int row = (gid >> 6) * 8 + g8;
    if (row >= NTOT) return;
    float4 sa, sb;
    agg_row8(row, l8, g8, rp, entries, F0, sa, sb);
    uint2 pa = pack4(sa), pb = pack4(sb);
    *reinterpret_cast<uint4*>(H1 + (size_t)row * DIM + l8 * 8) =
        make_uint4(pa.x, pa.y, pb.x, pb.y);
}

// ---------------- layer 2 (listed rows) + out += 0.25*H1 ----------------
__global__ void agg2_add1_kernel(const int* __restrict__ rp,
                                 const int2* __restrict__ entries,
                                 const unsigned short* __restrict__ H1,
                                 unsigned short* __restrict__ H2,
                                 const int* __restrict__ list,
                                 const int* __restrict__ count,
                                 const int* __restrict__ users,
                                 const int* __restrict__ pos,
                                 const int* __restrict__ neg,
                                 float* __restrict__ out)
{
    int bid = blockIdx.x;
    if (bid < AB8) {
        int gid = bid * 256 + threadIdx.x;
        int lane = gid & 63;
        int g8 = lane >> 3;
        int l8 = lane & 7;
        int idx8 = (gid >> 6) * 8 + g8;
        int n = *count;
        if (idx8 >= n) return;
        int row = list[idx8];
        float4 sa, sb;
        agg_row8(row, l8, g8, rp, entries, H1, sa, sb);
        uint2 pa = pack4(sa), pb = pack4(sb);
        *reinterpret_cast<uint4*>(H2 + (size_t)row * DIM + l8 * 8) =
            make_uint4(pa.x, pa.y, pb.x, pb.y);
    } else {
        int idx = (bid - AB8) * 256 + threadIdx.x;
        int row = idx >> 4;
        if (row >= NOUT) return;
        int d4 = (idx & 15) << 2;
        int bucket = out_bucket(row, users, pos, neg);
        uint2 v = *reinterpret_cast<const uint2*>(H1 + (size_t)bucket * DIM + d4);
        float* op = out + (size_t)row * DIM + d4;
        float4 o = *reinterpret_cast<const float4*>(op);
        o.x += 0.25f * __uint_as_float(v.x << 16);
        o.y += 0.25f * __uint_as_float(v.x & 0xffff0000u);
        o.z += 0.25f * __uint_as_float(v.y << 16);
        o.w += 0.25f * __uint_as_float(v.y & 0xffff0000u);
        *reinterpret_cast<float4*>(op) = o;
    }
}

// ---------------- layer 3 at output rows, H2 add in-thread ----------------
__global__ void aggout_add2_kernel(const int* __restrict__ rp,
                                   const int2* __restrict__ entries,
                                   const unsigned short* __restrict__ H2,
                                   const int* __restrict__ users,
                                   const int* __restrict__ pos,
                                   const int* __restrict__ neg,
                                   float* __restrict__ out)
{
    int gid = blockIdx.x * 256 + threadIdx.x;
    int lane = gid & 63;
    int g8 = lane >> 3;
    int l8 = lane & 7;
    int orow = (gid >> 6) * 8 + g8;
    if (orow >= NOUT) return;
    int bucket = out_bucket(orow, users, pos, neg);
    float4 sa, sb;
    agg_row8(bucket, l8, g8, rp, entries, H2, sa, sb);
    uint4 v = *reinterpret_cast<const uint4*>(H2 + (size_t)bucket * DIM + l8 * 8);
    sa.x += __uint_as_float(v.x << 16);
    sa.y += __uint_as_float(v.x & 0xffff0000u);
    sa.z += __uint_as_float(v.y << 16);
    sa.w += __uint_as_float(v.y & 0xffff0000u);
    sb.x += __uint_as_float(v.z << 16);
    sb.y += __uint_as_float(v.z & 0xffff0000u);
    sb.z += __uint_as_float(v.w << 16);
    sb.w += __uint_as_float(v.w & 0xffff0000u);
    float* op = out + (size_t)orow * DIM + l8 * 8;
    float4 o0 = *reinterpret_cast<const float4*>(op);
    float4 o1 = *reinterpret_cast<const float4*>(op + 4);
    o0.x += 0.25f * sa.x; o0.y += 0.25f * sa.y;
    o0.z += 0.25f * sa.z; o0.w += 0.25f * sa.w;
    o1.x += 0.25f * sb.x; o1.y += 0.25f * sb.y;
    o1.z += 0.25f * sb.z; o1.w += 0.25f * sb.w;
    *reinterpret_cast<float4*>(op) = o0;
    *reinterpret_cast<float4*>(op + 4) = o1;
}

extern "C" void kernel_launch(void* const* d_in, const int* in_sizes, int n_in,
                              void* d_out, int out_size, void* d_ws, size_t ws_size,
                              hipStream_t stream)
{
    const float* user_feat = (const float*)d_in[0];
    const float* item_feat = (const float*)d_in[1];
    const int*   eu        = (const int*)d_in[2];
    const int*   ei        = (const int*)d_in[3];
    const float* norm      = (const float*)d_in[4];
    const int*   users     = (const int*)d_in[5];
    const int*   pos       = (const int*)d_in[6];
    const int*   neg       = (const int*)d_in[7];
    float* out = (float*)d_out;

    auto align256 = [](size_t x) { return (x + 255) & ~(size_t)255; };
    const size_t hBytes = (size_t)NTOT * DIM * sizeof(unsigned short);  // 38.4 MB

    char* p = (char*)d_ws;
    unsigned short* F0 = (unsigned short*)p; p += align256(hBytes);
    unsigned short* H1 = (unsigned short*)p; p += align256(hBytes);
    unsigned short* H2 = (unsigned short*)p; p += align256(hBytes);
    // memset region: partTotals(512) | bitmap(NTOT) | flags(NTOT) | count(16)
    int* partTotals = (int*)p; p += align256((size_t)(512 + 2 * NTOT + 16) * 4);
    int* bitmap = partTotals + 512;
    int* flags  = bitmap + NTOT;
    int* count  = flags + NTOT;
    int*  partStart = (int*)p;  p += align256(512 * 4);
    int*  gcur      = (int*)p;  p += align256(512 * 4);
    int*  rp        = (int*)p;  p += align256((size_t)(NTOT + 1) * 4);
    uint2* partBuf  = (uint2*)p; p += align256((size_t)2 * N_EDGES * 8);
    int*  list      = (int*)p;  p += align256((size_t)NTOT * 4);
    int2* entries   = (int2*)p; p += align256((size_t)2 * N_EDGES * 8);
    // total ~152 MB

    hipMemsetAsync(partTotals, 0, (size_t)(512 + 2 * NTOT + 16) * 4, stream);

    // A
    fused_pre_kernel<<<HA + CB + OB + BB, 256, 0, stream>>>(
        eu, ei, partTotals,
        (const float4*)user_feat, (const float4*)item_feat, F0,
        user_feat, item_feat, users, pos, neg, out, bitmap, flags);

    // S
    part_scan_kernel<<<1, 512, 0, stream>>>(partTotals, partStart, gcur);

    // B: partition scatter + edge-sweep flagging
    partition_kernel<<<HA + HA, 256, 0, stream>>>(
        eu, ei, norm, gcur, partBuf, bitmap, flags);

    // C: CSR build + compaction
    build_csr_kernel<<<NPART + CPB, 256, 0, stream>>>(
        partStart, partBuf, rp, entries, flags, list, count);

    // layer 1 (all rows)
    agg1_kernel<<<AB8, 256, 0, stream>>>(rp, entries, F0, H1);

    // layer 2 (listed rows) + out += 0.25*H1
    agg2_add1_kernel<<<AB8 + OB, 256, 0, stream>>>(
        rp, entries, H1, H2, list, count, users, pos, neg, out);

    // layer 3 at output rows with in-thread H2 add
    aggout_add2_kernel<<<NOUT / 32, 256, 0, stream>>>(
        rp, entries, H2, users, pos, neg, out);
}